// Round 1
// baseline (540.824 us; speedup 1.0000x reference)
//
#include <hip/hip_runtime.h>

#define Bn 16
#define Cn 128
#define Hn 128
#define Wn 128
#define HWn (Hn*Wn)
#define CHWn (Cn*HWn)
#define HALF 64
#define NTOT (Bn*HWn)   // per-channel reduction count = 262144

// ---------------- fused depthwise 3x3 + pointwise 64x64 (fusion channels 0..63) ----------------
// grid: Bn*Hn blocks (one image row each), 256 threads
__global__ __launch_bounds__(256) void dwpw_kernel(
    const float* __restrict__ x, const float* __restrict__ dw_w,
    const float* __restrict__ dw_b, const float* __restrict__ pw_w,
    const float* __restrict__ pw_b, float* __restrict__ out,
    float* __restrict__ stats)
{
  __shared__ float dw_lds[HALF*132];   // [k][px], pitch 132 (16B-aligned rows)
  __shared__ float wt[HALF*65];        // transposed pw_w: wt[k*65+c] = pw_w[c][k]
  __shared__ float sred[2*HALF];

  const int t = threadIdx.x;
  const int blk = blockIdx.x;
  const int b = blk >> 7;
  const int h = blk & 127;

  // load transposed pointwise weights (coalesced read, conflict-free LDS write)
  for (int i = t; i < HALF*HALF; i += 256) {
    int c = i >> 6, k = i & 63;
    wt[k*65 + c] = pw_w[i];
  }
  if (t < 2*HALF) sred[t] = 0.f;

  // phase 1: depthwise 3x3 pad=1 into LDS
  {
    const int px = t & 127;
    const int k0 = t >> 7;     // 0/1, wave-uniform
    const float* xb = x + (size_t)b * CHWn;
    for (int kk = 0; kk < 32; ++kk) {
      int k = k0 + 2*kk;
      const float* xc = xb + (size_t)(2*k) * HWn;
      const float* wk = dw_w + k*9;
      float acc = dw_b[k];
      #pragma unroll
      for (int dr = 0; dr < 3; ++dr) {
        int r = h + dr - 1;
        if (r >= 0 && r < Hn) {
          const float* rp = xc + r*Wn;
          float xm = (px > 0)    ? rp[px-1] : 0.f;
          float x0 = rp[px];
          float xp = (px < Wn-1) ? rp[px+1] : 0.f;
          acc += wk[dr*3+0]*xm + wk[dr*3+1]*x0 + wk[dr*3+2]*xp;
        }
      }
      dw_lds[k*132 + px] = acc;
    }
  }
  __syncthreads();

  // phase 2: pointwise. lane = out channel c, each wave owns 32 pixels.
  // dw reads are wave-uniform (broadcast); stats accumulate per-lane in registers.
  {
    const int lane = t & 63;
    const int p0 = (t >> 6) * 32;
    float val[32];
    float bias = pw_b[lane];
    #pragma unroll
    for (int i = 0; i < 32; ++i) val[i] = bias;
    for (int k = 0; k < 64; ++k) {
      float wkc = wt[k*65 + lane];
      #pragma unroll
      for (int ii = 0; ii < 8; ++ii) {
        float4 dv = *(const float4*)&dw_lds[k*132 + p0 + ii*4];
        val[ii*4+0] += wkc * dv.x;
        val[ii*4+1] += wkc * dv.y;
        val[ii*4+2] += wkc * dv.z;
        val[ii*4+3] += wkc * dv.w;
      }
    }
    float s = 0.f, sq = 0.f;
    #pragma unroll
    for (int i = 0; i < 32; ++i) { float v = val[i]; s += v; sq += v*v; }
    // write back into dw_lds (each wave touches only its own 32 columns -> no cross-wave hazard)
    #pragma unroll
    for (int i = 0; i < 32; ++i) dw_lds[lane*132 + p0 + i] = val[i];
    atomicAdd(&sred[lane], s);
    atomicAdd(&sred[HALF + lane], sq);
  }
  __syncthreads();

  // phase 3: coalesced float4 stores + one global atomic per channel per block
  {
    const size_t ob = (size_t)b * CHWn + (size_t)h * Wn;
    for (int qq = t; qq < 2048; qq += 256) {
      int c = qq >> 5;
      int px4 = (qq & 31) << 2;
      float4 v = *(const float4*)&dw_lds[c*132 + px4];
      *(float4*)(out + ob + (size_t)c * HWn + px4) = v;
    }
    if (t < HALF) atomicAdd(&stats[t], sred[t]);
    else if (t < 2*HALF) atomicAdd(&stats[128 + (t - HALF)], sred[t]);
  }
}

// ---------------- dilated depthwise (fusion channels 64..127) ----------------
// grid: Bn * 64 * (Hn/8) blocks, 256 threads; block = (b, m, 8-row tile)
__global__ __launch_bounds__(256) void mcc_kernel(
    const float* __restrict__ x, const float* __restrict__ mcc_w,
    const float* __restrict__ mcc_b, float* __restrict__ out,
    float* __restrict__ stats)
{
  const int t  = threadIdx.x;
  const int blk = blockIdx.x;
  const int hb = blk & 15;
  const int m  = (blk >> 4) & 63;
  const int b  = blk >> 10;
  const int j  = m & 3;
  const int d  = j + 1;
  const int px4 = (t & 31) << 2;
  const int r  = t >> 5;          // 0..7
  const int h  = (hb << 3) + r;

  const float* xc = x + (size_t)b*CHWn + (size_t)(2*m+1)*HWn;
  const float* wj = mcc_w + j*9;
  const float bj = mcc_b[j];
  float v[4] = {bj, bj, bj, bj};
  #pragma unroll
  for (int dr = 0; dr < 3; ++dr) {
    int rr = h + (dr-1)*d;
    if (rr >= 0 && rr < Hn) {
      const float* rp = xc + rr*Wn;
      float wa = wj[dr*3+0], wb = wj[dr*3+1], wc = wj[dr*3+2];
      #pragma unroll
      for (int i = 0; i < 4; ++i) {
        int p = px4 + i;
        float a0 = (p >= d)   ? rp[p-d] : 0.f;
        float a1 = rp[p];
        float a2 = (p+d < Wn) ? rp[p+d] : 0.f;
        v[i] += wa*a0 + wb*a1 + wc*a2;
      }
    }
  }
  float4 o; o.x = v[0]; o.y = v[1]; o.z = v[2]; o.w = v[3];
  *(float4*)(out + (size_t)b*CHWn + (size_t)(HALF+m)*HWn + (size_t)h*Wn + px4) = o;

  float ts = v[0]+v[1]+v[2]+v[3];
  float tq = v[0]*v[0]+v[1]*v[1]+v[2]*v[2]+v[3]*v[3];
  for (int off = 32; off > 0; off >>= 1) {
    ts += __shfl_down(ts, off);
    tq += __shfl_down(tq, off);
  }
  __shared__ float red[8];
  const int wv = t >> 6;
  if ((t & 63) == 0) { red[wv] = ts; red[4+wv] = tq; }
  __syncthreads();
  if (t == 0) {
    atomicAdd(&stats[HALF + m],       red[0]+red[1]+red[2]+red[3]);
    atomicAdd(&stats[128 + HALF + m], red[4]+red[5]+red[6]+red[7]);
  }
}

// ---------------- stats -> per-channel scale/shift ----------------
__global__ void finalize_kernel(const float* __restrict__ stats,
    const float* __restrict__ gamma, const float* __restrict__ beta,
    float* __restrict__ ss)
{
  int c = threadIdx.x;          // 128 threads
  const float n = (float)NTOT;
  float mean = stats[c] / n;
  float var  = stats[128 + c] / n - mean*mean;
  float inv  = 1.0f / sqrtf(var + 1e-5f);
  float sc = gamma[c] * inv;
  float sh = beta[c] - mean * sc;
  ss[2*c]   = sc;
  ss[2*c+1] = sh;
}

// ---------------- in-place normalize + relu ----------------
__global__ __launch_bounds__(256) void norm_kernel(float* __restrict__ out,
                                                   const float* __restrict__ ss)
{
  const int nq = Bn*CHWn/4;   // 8388608 float4s
  for (int q = blockIdx.x*256 + threadIdx.x; q < nq; q += gridDim.x*256) {
    int c = (q >> 12) & 127;  // HW/4 = 4096 float4 per channel-plane
    float sc = ss[2*c], sh = ss[2*c+1];
    float4 v = ((const float4*)out)[q];
    v.x = fmaxf(fmaf(v.x, sc, sh), 0.f);
    v.y = fmaxf(fmaf(v.y, sc, sh), 0.f);
    v.z = fmaxf(fmaf(v.z, sc, sh), 0.f);
    v.w = fmaxf(fmaf(v.w, sc, sh), 0.f);
    ((float4*)out)[q] = v;
  }
}

extern "C" void kernel_launch(void* const* d_in, const int* in_sizes, int n_in,
                              void* d_out, int out_size, void* d_ws, size_t ws_size,
                              hipStream_t stream)
{
  (void)in_sizes; (void)n_in; (void)out_size; (void)ws_size;
  const float* x     = (const float*)d_in[0];
  const float* dw_w  = (const float*)d_in[1];
  const float* dw_b  = (const float*)d_in[2];
  const float* pw_w  = (const float*)d_in[3];
  const float* pw_b  = (const float*)d_in[4];
  const float* mcc_w = (const float*)d_in[5];
  const float* mcc_b = (const float*)d_in[6];
  const float* gamma = (const float*)d_in[7];
  const float* beta  = (const float*)d_in[8];
  float* out   = (float*)d_out;
  float* stats = (float*)d_ws;        // [0..127] sum, [128..255] sumsq
  float* ss    = stats + 256;         // [256..511] interleaved scale/shift

  hipMemsetAsync(d_ws, 0, 256*sizeof(float), stream);
  dwpw_kernel<<<Bn*Hn, 256, 0, stream>>>(x, dw_w, dw_b, pw_w, pw_b, out, stats);
  mcc_kernel<<<Bn*HALF*(Hn/8), 256, 0, stream>>>(x, mcc_w, mcc_b, out, stats);
  finalize_kernel<<<1, 128, 0, stream>>>(stats, gamma, beta, ss);
  norm_kernel<<<8192, 256, 0, stream>>>(out, ss);
}

// Round 2
// 433.372 us; speedup vs baseline: 1.2479x; 1.2479x over previous
//
#include <hip/hip_runtime.h>

#define Bn 16
#define Cn 128
#define Hn 128
#define Wn 128
#define HWn (Hn*Wn)
#define CHWn (Cn*HWn)
#define HALF 64
#define NTOT (Bn*HWn)   // per-channel reduction count = 262144

__device__ __forceinline__ float4 fma4(float s, float4 v, float4 a) {
  a.x = fmaf(s, v.x, a.x); a.y = fmaf(s, v.y, a.y);
  a.z = fmaf(s, v.z, a.z); a.w = fmaf(s, v.w, a.w);
  return a;
}

// ---------------- fused depthwise 3x3 + pointwise 64x64 (fusion channels 0..63) ----------------
// grid: Bn*Hn blocks (one image row each), 256 threads
__global__ __launch_bounds__(256) void dwpw_kernel(
    const float* __restrict__ x, const float* __restrict__ dw_w,
    const float* __restrict__ dw_b, const float* __restrict__ pw_w,
    const float* __restrict__ pw_b, float* __restrict__ out,
    float* __restrict__ stats)
{
  __shared__ float dw_lds[HALF*132];   // [k][px], pitch 132 (16B-aligned rows)
  __shared__ float wt[HALF*68];        // transposed pw_w: wt[k*68+c] = pw_w[c][k]
  __shared__ float sred[2*HALF];

  const int t = threadIdx.x;
  const int b = blockIdx.x >> 7;
  const int h = blockIdx.x & 127;

  // transposed pointwise weights into LDS (read coalesced)
  for (int i = t; i < HALF*HALF; i += 256) {
    int c = i >> 6, k = i & 63;
    wt[k*68 + c] = pw_w[i];
  }
  if (t < 2*HALF) sred[t] = 0.f;

  // phase 1: depthwise 3x3 pad=1 -> LDS, float4 per thread-iter
  {
    const int px4 = (t & 31) << 2;     // 0..124
    const int k0 = t >> 5;             // 0..7
    const float* xb = x + (size_t)b * CHWn;
    #pragma unroll
    for (int i = 0; i < 8; ++i) {
      const int k = k0*8 + i;
      const float* xc = xb + (size_t)(2*k) * HWn;
      const float* wk = dw_w + k*9;
      const float bk = dw_b[k];
      float4 acc = make_float4(bk, bk, bk, bk);
      #pragma unroll
      for (int dr = 0; dr < 3; ++dr) {
        const int r = h + dr - 1;
        if (r >= 0 && r < Hn) {
          const float* rp = xc + r*Wn;
          float4 B4 = *(const float4*)(rp + px4);
          float xl = (px4 > 0)   ? rp[px4-1] : 0.f;
          float xr = (px4 < 124) ? rp[px4+4] : 0.f;
          float4 L = make_float4(xl, B4.x, B4.y, B4.z);
          float4 R = make_float4(B4.y, B4.z, B4.w, xr);
          acc = fma4(wk[dr*3+0], L, acc);
          acc = fma4(wk[dr*3+1], B4, acc);
          acc = fma4(wk[dr*3+2], R, acc);
        }
      }
      *(float4*)&dw_lds[k*132 + px4] = acc;
    }
  }
  __syncthreads();

  // phase 2: register-tiled GEMM  C[64c x 128px] = W[64c x 64k] * D[64k x 128px]
  // wave w owns px [32w, 32w+32); lane = cg(0..15) + 16*pg(0..3); lane tile = 4c x 8px
  {
    const int lane = t & 63;
    const int wv   = t >> 6;
    const int cg   = lane & 15;
    const int pg   = lane >> 4;
    const int c0   = cg << 2;
    const int px0  = wv*32 + pg*8;

    float4 bias = *(const float4*)&pw_b[c0];
    float4 aA[4], aB[4];
    aA[0] = make_float4(bias.x, bias.x, bias.x, bias.x); aB[0] = aA[0];
    aA[1] = make_float4(bias.y, bias.y, bias.y, bias.y); aB[1] = aA[1];
    aA[2] = make_float4(bias.z, bias.z, bias.z, bias.z); aB[2] = aA[2];
    aA[3] = make_float4(bias.w, bias.w, bias.w, bias.w); aB[3] = aA[3];

    #pragma unroll 4
    for (int k = 0; k < 64; ++k) {
      float4 wf = *(const float4*)&wt[k*68 + c0];
      float4 dA = *(const float4*)&dw_lds[k*132 + px0];
      float4 dB = *(const float4*)&dw_lds[k*132 + px0 + 4];
      aA[0] = fma4(wf.x, dA, aA[0]); aB[0] = fma4(wf.x, dB, aB[0]);
      aA[1] = fma4(wf.y, dA, aA[1]); aB[1] = fma4(wf.y, dB, aB[1]);
      aA[2] = fma4(wf.z, dA, aA[2]); aB[2] = fma4(wf.z, dB, aB[2]);
      aA[3] = fma4(wf.w, dA, aA[3]); aB[3] = fma4(wf.w, dB, aB[3]);
    }

    // direct global stores (16 c-rows x 64B contiguous per instr)
    const size_t ob = (size_t)b*CHWn + (size_t)h*Wn + px0;
    #pragma unroll
    for (int ci = 0; ci < 4; ++ci) {
      *(float4*)(out + ob + (size_t)(c0+ci)*HWn)     = aA[ci];
      *(float4*)(out + ob + (size_t)(c0+ci)*HWn + 4) = aB[ci];
    }

    // per-channel stats: sum over 8 px, then reduce over the 4 pg lanes
    float s[4], q[4];
    #pragma unroll
    for (int ci = 0; ci < 4; ++ci) {
      float4 u = aA[ci], v = aB[ci];
      s[ci] = (u.x+u.y+u.z+u.w) + (v.x+v.y+v.z+v.w);
      q[ci] = u.x*u.x+u.y*u.y+u.z*u.z+u.w*u.w
            + v.x*v.x+v.y*v.y+v.z*v.z+v.w*v.w;
    }
    #pragma unroll
    for (int ci = 0; ci < 4; ++ci) {
      s[ci] += __shfl_xor(s[ci], 16); s[ci] += __shfl_xor(s[ci], 32);
      q[ci] += __shfl_xor(q[ci], 16); q[ci] += __shfl_xor(q[ci], 32);
    }
    if (pg == 0) {
      #pragma unroll
      for (int ci = 0; ci < 4; ++ci) {
        atomicAdd(&sred[c0+ci], s[ci]);
        atomicAdd(&sred[HALF+c0+ci], q[ci]);
      }
    }
  }
  __syncthreads();
  if (t < HALF)        atomicAdd(&stats[t], sred[t]);             // sum, c=t
  else if (t < 2*HALF) atomicAdd(&stats[64 + t], sred[t]);        // sq -> stats[128+(t-64)]
}

// ---------------- dilated depthwise (fusion channels 64..127) ----------------
template<int D> __device__ __forceinline__ float4 shiftL(float4 A, float4 B) {
  if (D == 1) return make_float4(A.w, B.x, B.y, B.z);
  if (D == 2) return make_float4(A.z, A.w, B.x, B.y);
  if (D == 3) return make_float4(A.y, A.z, A.w, B.x);
  return A;
}
template<int D> __device__ __forceinline__ float4 shiftR(float4 B, float4 C) {
  if (D == 1) return make_float4(B.y, B.z, B.w, C.x);
  if (D == 2) return make_float4(B.z, B.w, C.x, C.y);
  if (D == 3) return make_float4(B.w, C.x, C.y, C.z);
  return C;
}

template<int D>
__device__ __forceinline__ void mcc_compute(
    const float* __restrict__ xc, const float* __restrict__ wj, float bj,
    float* __restrict__ outp, float* lds, int t, int h0, float& s, float& q)
{
  const int R = 8 + 2*D;
  for (int idx = t; idx < R*32; idx += 256) {
    int r = idx >> 5, p4 = (idx & 31) << 2;
    int gr = h0 - D + r;
    float4 v = make_float4(0.f,0.f,0.f,0.f);
    if (gr >= 0 && gr < Hn) v = *(const float4*)(xc + gr*Wn + p4);
    *(float4*)&lds[r*128 + p4] = v;
  }
  __syncthreads();
  const int px4 = (t & 31) << 2;
  const int rl  = t >> 5;            // 0..7
  float4 acc = make_float4(bj, bj, bj, bj);
  #pragma unroll
  for (int dr = 0; dr < 3; ++dr) {
    const float* row = &lds[(rl + dr*D)*128];
    float4 B4 = *(const float4*)(row + px4);
    float4 A4 = make_float4(0.f,0.f,0.f,0.f);
    float4 C4 = make_float4(0.f,0.f,0.f,0.f);
    if (px4 > 0)   A4 = *(const float4*)(row + px4 - 4);
    if (px4 < 124) C4 = *(const float4*)(row + px4 + 4);
    acc = fma4(wj[dr*3+0], shiftL<D>(A4, B4), acc);
    acc = fma4(wj[dr*3+1], B4, acc);
    acc = fma4(wj[dr*3+2], shiftR<D>(B4, C4), acc);
  }
  *(float4*)(outp + (h0 + rl)*Wn + px4) = acc;
  s = acc.x + acc.y + acc.z + acc.w;
  q = acc.x*acc.x + acc.y*acc.y + acc.z*acc.z + acc.w*acc.w;
}

// grid: Bn * 64 * (Hn/8) blocks; block = (b, m, 8-row tile)
__global__ __launch_bounds__(256) void mcc_kernel(
    const float* __restrict__ x, const float* __restrict__ mcc_w,
    const float* __restrict__ mcc_b, float* __restrict__ out,
    float* __restrict__ stats)
{
  __shared__ float lds[16*128];
  __shared__ float red[8];
  const int t  = threadIdx.x;
  const int hb = blockIdx.x & 15;
  const int m  = (blockIdx.x >> 4) & 63;
  const int b  = blockIdx.x >> 10;
  const int j  = m & 3;
  const int h0 = hb << 3;

  const float* xc = x + (size_t)b*CHWn + (size_t)(2*m+1)*HWn;
  float* outp = out + (size_t)b*CHWn + (size_t)(HALF+m)*HWn;
  const float* wj = mcc_w + j*9;
  const float bj = mcc_b[j];

  float s = 0.f, q = 0.f;
  switch (j) {
    case 0: mcc_compute<1>(xc, wj, bj, outp, lds, t, h0, s, q); break;
    case 1: mcc_compute<2>(xc, wj, bj, outp, lds, t, h0, s, q); break;
    case 2: mcc_compute<3>(xc, wj, bj, outp, lds, t, h0, s, q); break;
    default: mcc_compute<4>(xc, wj, bj, outp, lds, t, h0, s, q); break;
  }

  #pragma unroll
  for (int off = 32; off > 0; off >>= 1) {
    s += __shfl_down(s, off);
    q += __shfl_down(q, off);
  }
  const int wv = t >> 6;
  if ((t & 63) == 0) { red[wv] = s; red[4+wv] = q; }
  __syncthreads();
  if (t == 0) {
    atomicAdd(&stats[HALF + m],       red[0]+red[1]+red[2]+red[3]);
    atomicAdd(&stats[128 + HALF + m], red[4]+red[5]+red[6]+red[7]);
  }
}

// ---------------- normalize + relu (finalize fused in) ----------------
__global__ __launch_bounds__(256) void norm_kernel(float* __restrict__ out,
    const float* __restrict__ stats, const float* __restrict__ gamma,
    const float* __restrict__ beta)
{
  __shared__ float ssc[128], ssh[128];
  const int t = threadIdx.x;
  if (t < 128) {
    const float n = (float)NTOT;
    float mean = stats[t] / n;
    float var  = stats[128 + t] / n - mean*mean;
    float inv  = 1.0f / sqrtf(var + 1e-5f);
    float sc = gamma[t] * inv;
    ssc[t] = sc;
    ssh[t] = beta[t] - mean * sc;
  }
  __syncthreads();
  const int nq = Bn*CHWn/4;   // 8388608 float4s
  for (int qi = blockIdx.x*256 + t; qi < nq; qi += gridDim.x*256) {
    int c = (qi >> 12) & 127;
    float sc = ssc[c], sh = ssh[c];
    float4 v = ((const float4*)out)[qi];
    v.x = fmaxf(fmaf(v.x, sc, sh), 0.f);
    v.y = fmaxf(fmaf(v.y, sc, sh), 0.f);
    v.z = fmaxf(fmaf(v.z, sc, sh), 0.f);
    v.w = fmaxf(fmaf(v.w, sc, sh), 0.f);
    ((float4*)out)[qi] = v;
  }
}

extern "C" void kernel_launch(void* const* d_in, const int* in_sizes, int n_in,
                              void* d_out, int out_size, void* d_ws, size_t ws_size,
                              hipStream_t stream)
{
  (void)in_sizes; (void)n_in; (void)out_size; (void)ws_size;
  const float* x     = (const float*)d_in[0];
  const float* dw_w  = (const float*)d_in[1];
  const float* dw_b  = (const float*)d_in[2];
  const float* pw_w  = (const float*)d_in[3];
  const float* pw_b  = (const float*)d_in[4];
  const float* mcc_w = (const float*)d_in[5];
  const float* mcc_b = (const float*)d_in[6];
  const float* gamma = (const float*)d_in[7];
  const float* beta  = (const float*)d_in[8];
  float* out   = (float*)d_out;
  float* stats = (float*)d_ws;        // [0..127] sum, [128..255] sumsq

  hipMemsetAsync(d_ws, 0, 256*sizeof(float), stream);
  dwpw_kernel<<<Bn*Hn, 256, 0, stream>>>(x, dw_w, dw_b, pw_w, pw_b, out, stats);
  mcc_kernel<<<Bn*HALF*(Hn/8), 256, 0, stream>>>(x, mcc_w, mcc_b, out, stats);
  norm_kernel<<<8192, 256, 0, stream>>>(out, stats, gamma, beta);
}

// Round 4
// 369.812 us; speedup vs baseline: 1.4624x; 1.1719x over previous
//
#include <hip/hip_runtime.h>
#include <hip/hip_bf16.h>

#define Bn 16
#define Cn 128
#define Hn 128
#define Wn 128
#define HWn (Hn*Wn)
#define CHWn (Cn*HWn)
#define HALF 64
#define NTOT (Bn*HWn)   // per-channel reduction count = 262144

__device__ __forceinline__ float4 fma4(float s, float4 v, float4 a) {
  a.x = fmaf(s, v.x, a.x); a.y = fmaf(s, v.y, a.y);
  a.z = fmaf(s, v.z, a.z); a.w = fmaf(s, v.w, a.w);
  return a;
}
__device__ __forceinline__ unsigned pk2(float a, float b) {
  union { __hip_bfloat162 h; unsigned u; } cv;
  cv.h.x = __float2bfloat16(a); cv.h.y = __float2bfloat16(b);
  return cv.u;
}
__device__ __forceinline__ float2 upk2(unsigned u) {
  union { unsigned u; __hip_bfloat162 h; } cv; cv.u = u;
  return make_float2(__bfloat162float(cv.h.x), __bfloat162float(cv.h.y));
}

// ---------------- tiny: transpose pw_w [c][k] -> wsT [k][c] ----------------
__global__ void transpose_pw(const float* __restrict__ pw_w, float* __restrict__ wsT) {
  int i = blockIdx.x*256 + threadIdx.x;   // 4096
  int co = i >> 6, ki = i & 63;
  wsT[ki*64 + co] = pw_w[i];
}

// row contribution with shuffle-sourced halo (row = 32 contiguous lanes)
__device__ __forceinline__ float4 row3(float4 acc, float4 B, float wa, float wb,
                                       float wc, int lane31) {
  float xl = __shfl_up(B.w, 1);
  float xr = __shfl_down(B.x, 1);
  if (lane31 == 0)  xl = 0.f;
  if (lane31 == 31) xr = 0.f;
  float4 L = make_float4(xl, B.x, B.y, B.z);
  float4 R = make_float4(B.y, B.z, B.w, xr);
  acc = fma4(wa, L, acc);
  acc = fma4(wb, B, acc);
  acc = fma4(wc, R, acc);
  return acc;
}

// ---------------- fused depthwise 3x3 + pointwise 64x64 (channels 0..63) ----------------
// grid: Bn*Hn blocks (one image row each), 256 threads
template<bool BF16>
__global__ __launch_bounds__(256, 3) void dwpw_kernel(
    const float* __restrict__ x, const float* __restrict__ wsT,
    const float* __restrict__ dw_w, const float* __restrict__ dw_b,
    const float* __restrict__ pw_b, float* __restrict__ outf,
    __hip_bfloat16* __restrict__ outh, float* __restrict__ stats)
{
  __shared__ float dw_lds[HALF*128];   // 32 KB, [k][px]
  __shared__ float wt[HALF*64];        // 16 KB, [k][c]
  __shared__ float dww[640];           // [j][64] j=0..8 weights, [576+k] bias
  __shared__ float sred[128];

  const int t = threadIdx.x;
  const int b = blockIdx.x >> 7;
  const int h = blockIdx.x & 127;

  // stage pw weights (coalesced global, conflict-free LDS)
  #pragma unroll
  for (int i = 0; i < 4; ++i)
    ((float4*)wt)[t + 256*i] = ((const float4*)wsT)[t + 256*i];
  // stage dw weights [j][k] + bias
  for (int i = t; i < 576; i += 256) {
    int k = i / 9, j = i - k*9;
    dww[j*64 + k] = dw_w[i];
  }
  if (t < 64)  dww[576 + t] = dw_b[t];
  if (t < 128) sred[t] = 0.f;
  __syncthreads();   // <<< R4 FIX: dww/wt staging must be visible before phase 1 reads dww

  // phase 1: depthwise 3x3 pad=1 -> LDS
  {
    const int lane31 = t & 31;
    const int px4 = lane31 << 2;
    const int k0 = t >> 5;             // 0..7
    const float* xb = x + (size_t)b*CHWn + (size_t)h*Wn + px4;
    const bool hasU = (h > 0), hasD = (h < Hn-1);
    const float4 z4 = make_float4(0.f,0.f,0.f,0.f);
    #pragma unroll
    for (int i = 0; i < 8; ++i) {
      const int k = k0*8 + i;
      const float* xc = xb + (size_t)(2*k)*HWn;
      float4 r0 = hasU ? *(const float4*)(xc - Wn) : z4;
      float4 r1 = *(const float4*)xc;
      float4 r2 = hasD ? *(const float4*)(xc + Wn) : z4;
      float bk = dww[576 + k];
      float4 a = make_float4(bk, bk, bk, bk);
      a = row3(a, r0, dww[0*64+k], dww[1*64+k], dww[2*64+k], lane31);
      a = row3(a, r1, dww[3*64+k], dww[4*64+k], dww[5*64+k], lane31);
      a = row3(a, r2, dww[6*64+k], dww[7*64+k], dww[8*64+k], lane31);
      *(float4*)&dw_lds[k*128 + px4] = a;
    }
  }
  __syncthreads();

  // phase 2: register-tiled GEMM  C[64c x 128px] = W[64c x 64k] * D[64k x 128px]
  {
    const int lane = t & 63;
    const int wv   = t >> 6;
    const int cg   = lane & 15;
    const int pg   = lane >> 4;
    const int c0   = cg << 2;
    const int px0  = wv*32 + pg*8;

    float4 bias = *(const float4*)&pw_b[c0];
    float4 aA[4], aB[4];
    aA[0] = make_float4(bias.x, bias.x, bias.x, bias.x); aB[0] = aA[0];
    aA[1] = make_float4(bias.y, bias.y, bias.y, bias.y); aB[1] = aA[1];
    aA[2] = make_float4(bias.z, bias.z, bias.z, bias.z); aB[2] = aA[2];
    aA[3] = make_float4(bias.w, bias.w, bias.w, bias.w); aB[3] = aA[3];

    #pragma unroll 8
    for (int k = 0; k < 64; ++k) {
      float4 wf = *(const float4*)&wt[k*64 + c0];
      float4 dA = *(const float4*)&dw_lds[k*128 + px0];
      float4 dB = *(const float4*)&dw_lds[k*128 + px0 + 4];
      aA[0] = fma4(wf.x, dA, aA[0]); aB[0] = fma4(wf.x, dB, aB[0]);
      aA[1] = fma4(wf.y, dA, aA[1]); aB[1] = fma4(wf.y, dB, aB[1]);
      aA[2] = fma4(wf.z, dA, aA[2]); aB[2] = fma4(wf.z, dB, aB[2]);
      aA[3] = fma4(wf.w, dA, aA[3]); aB[3] = fma4(wf.w, dB, aB[3]);
    }

    const size_t ob = (size_t)b*CHWn + (size_t)h*Wn + px0;
    #pragma unroll
    for (int ci = 0; ci < 4; ++ci) {
      if (BF16) {
        uint4 pk;
        pk.x = pk2(aA[ci].x, aA[ci].y);
        pk.y = pk2(aA[ci].z, aA[ci].w);
        pk.z = pk2(aB[ci].x, aB[ci].y);
        pk.w = pk2(aB[ci].z, aB[ci].w);
        *(uint4*)(outh + ob + (size_t)(c0+ci)*HWn) = pk;
      } else {
        *(float4*)(outf + ob + (size_t)(c0+ci)*HWn)     = aA[ci];
        *(float4*)(outf + ob + (size_t)(c0+ci)*HWn + 4) = aB[ci];
      }
    }

    float s[4], q[4];
    #pragma unroll
    for (int ci = 0; ci < 4; ++ci) {
      float4 u = aA[ci], v = aB[ci];
      s[ci] = (u.x+u.y+u.z+u.w) + (v.x+v.y+v.z+v.w);
      q[ci] = u.x*u.x+u.y*u.y+u.z*u.z+u.w*u.w
            + v.x*v.x+v.y*v.y+v.z*v.z+v.w*v.w;
    }
    #pragma unroll
    for (int ci = 0; ci < 4; ++ci) {
      s[ci] += __shfl_xor(s[ci], 16); s[ci] += __shfl_xor(s[ci], 32);
      q[ci] += __shfl_xor(q[ci], 16); q[ci] += __shfl_xor(q[ci], 32);
    }
    if (pg == 0) {
      #pragma unroll
      for (int ci = 0; ci < 4; ++ci) {
        atomicAdd(&sred[c0+ci], s[ci]);
        atomicAdd(&sred[HALF+c0+ci], q[ci]);
      }
    }
  }
  __syncthreads();
  if (t < HALF)        atomicAdd(&stats[t], sred[t]);       // sum  c=t
  else if (t < 2*HALF) atomicAdd(&stats[64 + t], sred[t]);  // sq -> stats[128+(t-64)]
}

// ---------------- dilated depthwise (channels 64..127) ----------------
template<int D> __device__ __forceinline__ float4 shiftL(float4 A, float4 B) {
  if (D == 1) return make_float4(A.w, B.x, B.y, B.z);
  if (D == 2) return make_float4(A.z, A.w, B.x, B.y);
  if (D == 3) return make_float4(A.y, A.z, A.w, B.x);
  return A;
}
template<int D> __device__ __forceinline__ float4 shiftR(float4 B, float4 C) {
  if (D == 1) return make_float4(B.y, B.z, B.w, C.x);
  if (D == 2) return make_float4(B.z, B.w, C.x, C.y);
  if (D == 3) return make_float4(B.w, C.x, C.y, C.z);
  return C;
}

template<bool BF16, int D>
__device__ __forceinline__ void mcc_compute(
    const float* __restrict__ xc, const float* __restrict__ wj, float bj,
    float* __restrict__ outf, __hip_bfloat16* __restrict__ outh,
    float* lds, int t, int h0, float& s, float& q)
{
  const int R = 16 + 2*D;
  for (int idx = t; idx < R*32; idx += 256) {
    int r = idx >> 5, p4 = (idx & 31) << 2;
    int gr = h0 - D + r;
    float4 v = make_float4(0.f,0.f,0.f,0.f);
    if (gr >= 0 && gr < Hn) v = *(const float4*)(xc + gr*Wn + p4);
    *(float4*)&lds[r*128 + p4] = v;
  }
  __syncthreads();
  const int px4 = (t & 31) << 2;
  const int rl  = t >> 5;            // 0..7
  s = 0.f; q = 0.f;
  #pragma unroll
  for (int rr = 0; rr < 2; ++rr) {
    const int row = rl + rr*8;       // 0..15
    float4 acc = make_float4(bj, bj, bj, bj);
    #pragma unroll
    for (int dr = 0; dr < 3; ++dr) {
      const float* lrow = &lds[(row + dr*D)*128];
      float4 B4 = *(const float4*)(lrow + px4);
      float4 A4 = make_float4(0.f,0.f,0.f,0.f);
      float4 C4 = make_float4(0.f,0.f,0.f,0.f);
      if (px4 > 0)   A4 = *(const float4*)(lrow + px4 - 4);
      if (px4 < 124) C4 = *(const float4*)(lrow + px4 + 4);
      acc = fma4(wj[dr*3+0], shiftL<D>(A4, B4), acc);
      acc = fma4(wj[dr*3+1], B4, acc);
      acc = fma4(wj[dr*3+2], shiftR<D>(B4, C4), acc);
    }
    if (BF16) {
      uint2 pk; pk.x = pk2(acc.x, acc.y); pk.y = pk2(acc.z, acc.w);
      *(uint2*)(outh + (size_t)(h0+row)*Wn + px4) = pk;
    } else {
      *(float4*)(outf + (size_t)(h0+row)*Wn + px4) = acc;
    }
    s += acc.x + acc.y + acc.z + acc.w;
    q += acc.x*acc.x + acc.y*acc.y + acc.z*acc.z + acc.w*acc.w;
  }
}

// grid: Bn * 64 * (Hn/16) blocks; block = (b, m, 16-row tile)
template<bool BF16>
__global__ __launch_bounds__(256) void mcc_kernel(
    const float* __restrict__ x, const float* __restrict__ mcc_w,
    const float* __restrict__ mcc_b, float* __restrict__ outf,
    __hip_bfloat16* __restrict__ outh, float* __restrict__ stats)
{
  __shared__ float lds[24*128];
  __shared__ float red[8];
  const int t  = threadIdx.x;
  const int hb = blockIdx.x & 7;
  const int m  = (blockIdx.x >> 3) & 63;
  const int b  = blockIdx.x >> 9;
  const int j  = m & 3;
  const int h0 = hb << 4;

  const float* xc = x + (size_t)b*CHWn + (size_t)(2*m+1)*HWn;
  const size_t oo = (size_t)b*CHWn + (size_t)(HALF+m)*HWn;
  float* of = BF16 ? nullptr : outf + oo;
  __hip_bfloat16* oh = BF16 ? outh + oo : nullptr;
  const float* wj = mcc_w + j*9;
  const float bj = mcc_b[j];

  float s = 0.f, q = 0.f;
  switch (j) {
    case 0: mcc_compute<BF16,1>(xc, wj, bj, of, oh, lds, t, h0, s, q); break;
    case 1: mcc_compute<BF16,2>(xc, wj, bj, of, oh, lds, t, h0, s, q); break;
    case 2: mcc_compute<BF16,3>(xc, wj, bj, of, oh, lds, t, h0, s, q); break;
    default: mcc_compute<BF16,4>(xc, wj, bj, of, oh, lds, t, h0, s, q); break;
  }

  #pragma unroll
  for (int off = 32; off > 0; off >>= 1) {
    s += __shfl_down(s, off);
    q += __shfl_down(q, off);
  }
  const int wv = t >> 6;
  if ((t & 63) == 0) { red[wv] = s; red[4+wv] = q; }
  __syncthreads();
  if (t == 0) {
    atomicAdd(&stats[HALF + m],       red[0]+red[1]+red[2]+red[3]);
    atomicAdd(&stats[128 + HALF + m], red[4]+red[5]+red[6]+red[7]);
  }
}

// ---------------- normalize + relu: bf16 in (ws), fp32 out ----------------
__global__ __launch_bounds__(256) void norm_bf_kernel(
    const __hip_bfloat16* __restrict__ inh, float* __restrict__ out,
    const float* __restrict__ stats, const float* __restrict__ gamma,
    const float* __restrict__ beta)
{
  __shared__ float ssc[128], ssh[128];
  const int t = threadIdx.x;
  if (t < 128) {
    const float n = (float)NTOT;
    float mean = stats[t] / n;
    float var  = stats[128 + t] / n - mean*mean;
    float inv  = 1.0f / sqrtf(var + 1e-5f);
    float sc = gamma[t] * inv;
    ssc[t] = sc;
    ssh[t] = beta[t] - mean * sc;
  }
  __syncthreads();
  const int nq = Bn*CHWn/8;   // 4194304 groups of 8
  const uint4* in = (const uint4*)inh;
  for (int qi = blockIdx.x*256 + t; qi < nq; qi += gridDim.x*256) {
    int c = (qi >> 11) & 127;        // HWn/8 = 2048
    float sc = ssc[c], sh = ssh[c];
    uint4 p = in[qi];
    float2 f0 = upk2(p.x), f1 = upk2(p.y), f2 = upk2(p.z), f3 = upk2(p.w);
    float4 a, bq;
    a.x = fmaxf(fmaf(f0.x, sc, sh), 0.f);
    a.y = fmaxf(fmaf(f0.y, sc, sh), 0.f);
    a.z = fmaxf(fmaf(f1.x, sc, sh), 0.f);
    a.w = fmaxf(fmaf(f1.y, sc, sh), 0.f);
    bq.x = fmaxf(fmaf(f2.x, sc, sh), 0.f);
    bq.y = fmaxf(fmaf(f2.y, sc, sh), 0.f);
    bq.z = fmaxf(fmaf(f3.x, sc, sh), 0.f);
    bq.w = fmaxf(fmaf(f3.y, sc, sh), 0.f);
    *(float4*)(out + (size_t)qi*8)     = a;
    *(float4*)(out + (size_t)qi*8 + 4) = bq;
  }
}

// ---------------- normalize + relu: fp32 in-place fallback ----------------
__global__ __launch_bounds__(256) void norm_f32_kernel(float* __restrict__ out,
    const float* __restrict__ stats, const float* __restrict__ gamma,
    const float* __restrict__ beta)
{
  __shared__ float ssc[128], ssh[128];
  const int t = threadIdx.x;
  if (t < 128) {
    const float n = (float)NTOT;
    float mean = stats[t] / n;
    float var  = stats[128 + t] / n - mean*mean;
    float inv  = 1.0f / sqrtf(var + 1e-5f);
    float sc = gamma[t] * inv;
    ssc[t] = sc;
    ssh[t] = beta[t] - mean * sc;
  }
  __syncthreads();
  const int nq = Bn*CHWn/4;
  for (int qi = blockIdx.x*256 + t; qi < nq; qi += gridDim.x*256) {
    int c = (qi >> 12) & 127;
    float sc = ssc[c], sh = ssh[c];
    float4 v = ((const float4*)out)[qi];
    v.x = fmaxf(fmaf(v.x, sc, sh), 0.f);
    v.y = fmaxf(fmaf(v.y, sc, sh), 0.f);
    v.z = fmaxf(fmaf(v.z, sc, sh), 0.f);
    v.w = fmaxf(fmaf(v.w, sc, sh), 0.f);
    ((float4*)out)[qi] = v;
  }
}

extern "C" void kernel_launch(void* const* d_in, const int* in_sizes, int n_in,
                              void* d_out, int out_size, void* d_ws, size_t ws_size,
                              hipStream_t stream)
{
  (void)in_sizes; (void)n_in; (void)out_size;
  const float* x     = (const float*)d_in[0];
  const float* dw_w  = (const float*)d_in[1];
  const float* dw_b  = (const float*)d_in[2];
  const float* pw_w  = (const float*)d_in[3];
  const float* pw_b  = (const float*)d_in[4];
  const float* mcc_w = (const float*)d_in[5];
  const float* mcc_b = (const float*)d_in[6];
  const float* gamma = (const float*)d_in[7];
  const float* beta  = (const float*)d_in[8];
  float* out   = (float*)d_out;
  float* stats = (float*)d_ws;                       // 256 floats
  float* wsT   = (float*)((char*)d_ws + 1024);       // 16 KB transposed pw_w
  __hip_bfloat16* bf = (__hip_bfloat16*)((char*)d_ws + 17408);
  const size_t need = 17408 + (size_t)Bn*CHWn*2;     // bf16 fusion tensor
  const bool useBF = ws_size >= need;

  hipMemsetAsync(d_ws, 0, 1024, stream);
  transpose_pw<<<16, 256, 0, stream>>>(pw_w, wsT);
  if (useBF) {
    dwpw_kernel<true><<<Bn*Hn, 256, 0, stream>>>(x, wsT, dw_w, dw_b, pw_b, nullptr, bf, stats);
    mcc_kernel<true><<<Bn*HALF*(Hn/16), 256, 0, stream>>>(x, mcc_w, mcc_b, nullptr, bf, stats);
    norm_bf_kernel<<<8192, 256, 0, stream>>>(bf, out, stats, gamma, beta);
  } else {
    dwpw_kernel<false><<<Bn*Hn, 256, 0, stream>>>(x, wsT, dw_w, dw_b, pw_b, out, nullptr, stats);
    mcc_kernel<false><<<Bn*HALF*(Hn/16), 256, 0, stream>>>(x, mcc_w, mcc_b, out, nullptr, stats);
    norm_f32_kernel<<<8192, 256, 0, stream>>>(out, stats, gamma, beta);
  }
}